// Round 8
// baseline (297.441 us; speedup 1.0000x reference)
//
#include <hip/hip_runtime.h>
#include <math.h>

// GCN: out = Ahat @ (relu(Ahat @ X @ W1 + b1)) @ W2 + b2
// R1: dst-CSR + gather aggregation (no f32 atomics).
// R2/R3: parallel scan; f32 GEMM retile.
// R4: split-bf16 (hi+lo) 3-pass MFMA GEMM: A@W ~= Ahi@Whi + Ahi@Wlo + Alo@Whi.
// R5: GEMM waves fattened to 64 rows x 128 cols (latency fix).
// R6: gather ILP + prescaled layer-2 (pure adds).
// R7: feature-sliced XCD-localized gather: slice = blockIdx%8 -> each XCD's
//     L2 holds one 3.2 MB 16-float slice of the feature table (gathers served
//     from L2, not L3). Both layers prescaled (Xs = dinv*x precomputed).

constexpr int NN = 50000;
constexpr int NE = 640000;
constexpr int NPAD = 50048;          // rows padded to 64
constexpr int F_IN = 128;
constexpr int F_HID = 256;
constexpr int F_OUT = 128;

typedef __attribute__((ext_vector_type(8))) short bf16x8;   // 8 bf16 = 4 VGPRs
typedef __attribute__((ext_vector_type(4))) float f32x4;
typedef __attribute__((ext_vector_type(8))) unsigned short u16x8;

__device__ inline unsigned short f2bf(float v) {  // RNE f32->bf16
    unsigned int u = __float_as_uint(v);
    return (unsigned short)((u + 0x7fff + ((u >> 16) & 1)) >> 16);
}
__device__ inline float bf2f(unsigned short h) {
    return __uint_as_float(((unsigned int)h) << 16);
}

__global__ void k_zero_deg(int* __restrict__ deg) {
    int v = blockIdx.x * blockDim.x + threadIdx.x;
    if (v < NN) deg[v] = 0;
}

__global__ void k_count_deg(const int* __restrict__ dst, int* __restrict__ deg) {
    int e = blockIdx.x * blockDim.x + threadIdx.x;
    if (e < NE) atomicAdd(&deg[dst[e]], 1);
}

__global__ void k_dinv(const int* __restrict__ deg, float* __restrict__ dinv) {
    int v = blockIdx.x * blockDim.x + threadIdx.x;
    if (v < NN) dinv[v] = rsqrtf((float)(deg[v] + 1));  // +1 self loop
}

// ---- parallel exclusive scan of deg[NN] -> row_ptr ----
constexpr int SCB = 256;
constexpr int NCHUNK = (NN + SCB - 1) / SCB;  // 196

__global__ __launch_bounds__(SCB) void k_scan_blk(const int* __restrict__ deg,
                                                  int* __restrict__ row_ptr,
                                                  int* __restrict__ blk_sum) {
    __shared__ int sm[SCB];
    int i = blockIdx.x * SCB + threadIdx.x;
    int v = (i < NN) ? deg[i] : 0;
    sm[threadIdx.x] = v;
    __syncthreads();
    for (int off = 1; off < SCB; off <<= 1) {
        int t = (threadIdx.x >= off) ? sm[threadIdx.x - off] : 0;
        __syncthreads();
        sm[threadIdx.x] += t;
        __syncthreads();
    }
    if (i < NN) row_ptr[i] = sm[threadIdx.x] - v;
    if (threadIdx.x == SCB - 1) blk_sum[blockIdx.x] = sm[SCB - 1];
}

__global__ __launch_bounds__(SCB) void k_scan_top(const int* __restrict__ blk_sum,
                                                  int* __restrict__ blk_off) {
    __shared__ int sm[SCB];
    int v = (threadIdx.x < NCHUNK) ? blk_sum[threadIdx.x] : 0;
    sm[threadIdx.x] = v;
    __syncthreads();
    for (int off = 1; off < SCB; off <<= 1) {
        int t = (threadIdx.x >= off) ? sm[threadIdx.x - off] : 0;
        __syncthreads();
        sm[threadIdx.x] += t;
        __syncthreads();
    }
    if (threadIdx.x < NCHUNK) blk_off[threadIdx.x] = sm[threadIdx.x] - v;
}

__global__ __launch_bounds__(SCB) void k_scan_add(int* __restrict__ row_ptr,
                                                  const int* __restrict__ blk_off,
                                                  int* __restrict__ cursor) {
    int i = blockIdx.x * SCB + threadIdx.x;
    if (i < NN) {
        row_ptr[i] += blk_off[blockIdx.x];
        cursor[i] = 0;
    }
    if (i == 0) row_ptr[NN] = NE;
}

__global__ void k_fill_csr(const int* __restrict__ src, const int* __restrict__ dst,
                           const int* __restrict__ row_ptr, int* __restrict__ cursor,
                           int* __restrict__ csr_src) {
    int e = blockIdx.x * blockDim.x + threadIdx.x;
    if (e >= NE) return;
    int d = dst[e];
    int slot = row_ptr[d] + atomicAdd(&cursor[d], 1);
    csr_src[slot] = src[e];
}

// Xs[v][:] = dinv[v] * x[v][:]   (both layers then use pure-add gathers)
__global__ __launch_bounds__(256) void k_prescale(const float* __restrict__ x,
                                                  const float* __restrict__ dinv,
                                                  float* __restrict__ xs) {
    int gid = blockIdx.x * 256 + threadIdx.x;
    int v = gid >> 5, c = gid & 31;
    if (v >= NN) return;
    float di = dinv[v];
    float4 r = reinterpret_cast<const float4*>(x)[(size_t)v * 32 + c];
    r.x *= di; r.y *= di; r.z *= di; r.w *= di;
    reinterpret_cast<float4*>(xs)[(size_t)v * 32 + c] = r;
}

// Pack W[K][N] f32 -> fragment-native bf16 hi/lo: idx = ((kt*NT+nt)*64+lane)*8+e
template <int K, int N>
__global__ __launch_bounds__(256) void k_wpack(const float* __restrict__ W,
                                               unsigned short* __restrict__ hi,
                                               unsigned short* __restrict__ lo) {
    constexpr int NT = N / 16, KT = K / 32;
    int t = blockIdx.x * 256 + threadIdx.x;
    if (t >= KT * NT * 64) return;
    int lane = t & 63, nt = (t >> 6) % NT, kt = (t >> 6) / NT;
    int col = nt * 16 + (lane & 15), kg = lane >> 4;
    unsigned short hb[8], lb[8];
#pragma unroll
    for (int e = 0; e < 8; ++e) {
        int k = kt * 32 + kg * 8 + e;
        float v = W[(size_t)k * N + col];
        unsigned short h = f2bf(v);
        hb[e] = h;
        lb[e] = f2bf(v - bf2f(h));
    }
    *reinterpret_cast<u16x8*>(hi + (size_t)t * 8) = *reinterpret_cast<u16x8*>(hb);
    *reinterpret_cast<u16x8*>(lo + (size_t)t * 8) = *reinterpret_cast<u16x8*>(lb);
}

// Feature-sliced gather over prescaled features (pure adds):
//   out[v] = dinv[v] * (feat[v] + sum_{s in N(v)} feat[s])  (+bias)
// slice = blockIdx%8 -> XCD round-robin: each XCD's L2 caches one 16-float
// slice (50000*64B = 3.2 MB < 4 MB). 4 lanes/node, 64 nodes/block.
template <bool BIAS, bool SPLITOUT>
__global__ __launch_bounds__(256) void k_gather8(const float* __restrict__ feat,
                                                 const int* __restrict__ csr_src,
                                                 const int* __restrict__ row_ptr,
                                                 const float* __restrict__ dinv,
                                                 const float* __restrict__ bias,
                                                 float* __restrict__ out_f,
                                                 unsigned short* __restrict__ out_hi,
                                                 unsigned short* __restrict__ out_lo) {
    const int slice = blockIdx.x & 7;
    const int nb = blockIdx.x >> 3;
    const int node = nb * 64 + (threadIdx.x >> 2);
    const int c = slice * 4 + (threadIdx.x & 3);  // float4 index 0..31 in row
    if (node >= NN) return;
    const float4* f4 = reinterpret_cast<const float4*>(feat);
    float4 a = f4[(size_t)node * 32 + c];  // self (prescaled)
    int j = row_ptr[node], end = row_ptr[node + 1];
    for (; j + 7 < end; j += 8) {
        int s0 = csr_src[j + 0], s1 = csr_src[j + 1];
        int s2 = csr_src[j + 2], s3 = csr_src[j + 3];
        int s4 = csr_src[j + 4], s5 = csr_src[j + 5];
        int s6 = csr_src[j + 6], s7 = csr_src[j + 7];
        float4 r0 = f4[(size_t)s0 * 32 + c], r1 = f4[(size_t)s1 * 32 + c];
        float4 r2 = f4[(size_t)s2 * 32 + c], r3 = f4[(size_t)s3 * 32 + c];
        float4 r4 = f4[(size_t)s4 * 32 + c], r5 = f4[(size_t)s5 * 32 + c];
        float4 r6 = f4[(size_t)s6 * 32 + c], r7 = f4[(size_t)s7 * 32 + c];
        a.x += ((r0.x + r1.x) + (r2.x + r3.x)) + ((r4.x + r5.x) + (r6.x + r7.x));
        a.y += ((r0.y + r1.y) + (r2.y + r3.y)) + ((r4.y + r5.y) + (r6.y + r7.y));
        a.z += ((r0.z + r1.z) + (r2.z + r3.z)) + ((r4.z + r5.z) + (r6.z + r7.z));
        a.w += ((r0.w + r1.w) + (r2.w + r3.w)) + ((r4.w + r5.w) + (r6.w + r7.w));
    }
    for (; j < end; ++j) {
        float4 r = f4[(size_t)csr_src[j] * 32 + c];
        a.x += r.x; a.y += r.y; a.z += r.z; a.w += r.w;
    }
    float di = dinv[node];
    a.x *= di; a.y *= di; a.z *= di; a.w *= di;
    if (BIAS) {
        float4 b = reinterpret_cast<const float4*>(bias)[c];
        a.x += b.x; a.y += b.y; a.z += b.z; a.w += b.w;
    }
    if (SPLITOUT) {
        ushort4 hh, ll;
        hh.x = f2bf(a.x); ll.x = f2bf(a.x - bf2f(hh.x));
        hh.y = f2bf(a.y); ll.y = f2bf(a.y - bf2f(hh.y));
        hh.z = f2bf(a.z); ll.z = f2bf(a.z - bf2f(hh.z));
        hh.w = f2bf(a.w); ll.w = f2bf(a.w - bf2f(hh.w));
        *reinterpret_cast<ushort4*>(out_hi + (size_t)node * 128 + c * 4) = hh;
        *reinterpret_cast<ushort4*>(out_lo + (size_t)node * 128 + c * 4) = ll;
    } else {
        reinterpret_cast<float4*>(out_f)[(size_t)node * 32 + c] = a;
    }
}

// C[M,N] = A[M,K] @ W[K,N] via 3-pass split-bf16 MFMA 16x16x32.
// One wave per block; wave owns 64 rows x 128 cols (acc[4][8]).
// PRESCALE: multiply output row r by dscale[r] (folds dinv for gather-2).
template <int K, int N, bool RELU, bool BIAS, bool SPLITOUT, bool PRESCALE>
__global__ __launch_bounds__(64) void k_gemm_mfma(
    const unsigned short* __restrict__ Ahi, const unsigned short* __restrict__ Alo,
    const unsigned short* __restrict__ Bhi, const unsigned short* __restrict__ Blo,
    const float* __restrict__ bias, const float* __restrict__ dscale,
    unsigned short* __restrict__ Chi, unsigned short* __restrict__ Clo,
    float* __restrict__ Cf) {
    constexpr int NTall = N / 16, KT = K / 32;
    constexpr int WR = 4;
    constexpr int WC = 8;
    constexpr int NRB = NPAD / 64;
    const int lane = threadIdx.x;
    const int rb = blockIdx.x % NRB;
    const int cb = blockIdx.x / NRB;
    const int row0 = rb * 64;
    const int ct0 = cb * WC;
    const int r16 = lane & 15;
    const int kg = lane >> 4;

    f32x4 acc[WR][WC];
#pragma unroll
    for (int rt = 0; rt < WR; ++rt)
#pragma unroll
        for (int ct = 0; ct < WC; ++ct) acc[rt][ct] = (f32x4){0.f, 0.f, 0.f, 0.f};

    const unsigned short* pa_hi = Ahi + (size_t)(row0 + r16) * K + kg * 8;
    const unsigned short* pa_lo = Alo + (size_t)(row0 + r16) * K + kg * 8;
    const unsigned short* pb_hi = Bhi + (size_t)lane * 8;
    const unsigned short* pb_lo = Blo + (size_t)lane * 8;

#pragma unroll
    for (int kt = 0; kt < KT; ++kt) {
        bf16x8 ah[WR], al[WR];
#pragma unroll
        for (int rt = 0; rt < WR; ++rt) {
            ah[rt] = *reinterpret_cast<const bf16x8*>(pa_hi + (size_t)rt * 16 * K + kt * 32);
            al[rt] = *reinterpret_cast<const bf16x8*>(pa_lo + (size_t)rt * 16 * K + kt * 32);
        }
#pragma unroll
        for (int ct = 0; ct < WC; ++ct) {
            const int nt = ct0 + ct;
            bf16x8 bh = *reinterpret_cast<const bf16x8*>(pb_hi + (size_t)(kt * NTall + nt) * 512);
            bf16x8 bl = *reinterpret_cast<const bf16x8*>(pb_lo + (size_t)(kt * NTall + nt) * 512);
#pragma unroll
            for (int rt = 0; rt < WR; ++rt) {
                acc[rt][ct] = __builtin_amdgcn_mfma_f32_16x16x32_bf16(ah[rt], bh, acc[rt][ct], 0, 0, 0);
                acc[rt][ct] = __builtin_amdgcn_mfma_f32_16x16x32_bf16(ah[rt], bl, acc[rt][ct], 0, 0, 0);
                acc[rt][ct] = __builtin_amdgcn_mfma_f32_16x16x32_bf16(al[rt], bh, acc[rt][ct], 0, 0, 0);
            }
        }
    }

    // C/D layout: col = lane&15, row = (lane>>4)*4 + i
    const int ccol = lane & 15;
#pragma unroll
    for (int rt = 0; rt < WR; ++rt) {
        const int crow0 = row0 + rt * 16 + (lane >> 4) * 4;
#pragma unroll
        for (int ct = 0; ct < WC; ++ct) {
            int col = (ct0 + ct) * 16 + ccol;
            float bv = BIAS ? bias[col] : 0.f;
#pragma unroll
            for (int i = 0; i < 4; ++i) {
                float v = acc[rt][ct][i] + bv;
                if (RELU) v = fmaxf(v, 0.f);
                if (PRESCALE) v *= dscale[crow0 + i];
                size_t idx = (size_t)(crow0 + i) * N + col;
                if (SPLITOUT) {
                    unsigned short h = f2bf(v);
                    Chi[idx] = h;
                    Clo[idx] = f2bf(v - bf2f(h));
                } else {
                    Cf[idx] = v;
                }
            }
        }
    }
}

extern "C" void kernel_launch(void* const* d_in, const int* in_sizes, int n_in,
                              void* d_out, int out_size, void* d_ws, size_t ws_size,
                              hipStream_t stream) {
    const float* x  = (const float*)d_in[0];
    const int*   ei = (const int*)d_in[1];
    const float* W1 = (const float*)d_in[2];
    const float* b1 = (const float*)d_in[3];
    const float* W2 = (const float*)d_in[4];
    const float* b2 = (const float*)d_in[5];
    float* out = (float*)d_out;

    const int* src = ei;
    const int* dst = ei + NE;

    // workspace layout (all offsets 256-aligned):
    char* ws = (char*)d_ws;
    int*   deg     = (int*)ws;                               // 200 KB
    int*   cursor  = (int*)(ws + 262144);
    int*   row_ptr = (int*)(ws + 524288);
    float* dinv    = (float*)(ws + 786432);
    int*   csr_src = (int*)(ws + 1048576);                   // 2.56 MB
    int*   blk_sum = (int*)(ws + 3670016);
    int*   blk_off = (int*)(ws + 3674112);
    unsigned short* W1hi = (unsigned short*)(ws + 3678208);  // 64 KB each
    unsigned short* W1lo = (unsigned short*)(ws + 3743744);
    unsigned short* W2hi = (unsigned short*)(ws + 3809280);
    unsigned short* W2lo = (unsigned short*)(ws + 3874816);
    unsigned short* A1hi = (unsigned short*)(ws + 4194304);  // NPAD*128*2 = 12.81 MB
    unsigned short* A1lo = (unsigned short*)(ws + 17006592); // 12.81 MB
    unsigned short* H1hi = (unsigned short*)(ws + 29818880); // NPAD*256*2 = 25.62 MB
    unsigned short* H1lo = (unsigned short*)(ws + 55443456); // 25.62 MB
    float* Xs = (float*)(ws + 29818880);  // aliases H1hi (dead until GEMM-1 writes it)
    float* H2 = (float*)(ws + 4194304);   // aliases A1hi+A1lo (dead after GEMM-1)

    constexpr int BT = 256;
    const int gN = (NN + BT - 1) / BT;   // 196
    const int gE = (NE + BT - 1) / BT;   // 2500
    const int gP = (NN * 32 + BT - 1) / BT;  // 6250 (prescale)
    const int gG8 = ((NN + 63) / 64) * 8;    // 6256 (782 node-blks x 8 slices)
    constexpr int NRB = NPAD / 64;       // 782

    // CSR build
    k_zero_deg<<<gN, BT, 0, stream>>>(deg);
    k_count_deg<<<gE, BT, 0, stream>>>(dst, deg);
    k_dinv<<<gN, BT, 0, stream>>>(deg, dinv);
    k_scan_blk<<<NCHUNK, SCB, 0, stream>>>(deg, row_ptr, blk_sum);
    k_scan_top<<<1, SCB, 0, stream>>>(blk_sum, blk_off);
    k_scan_add<<<NCHUNK, SCB, 0, stream>>>(row_ptr, blk_off, cursor);
    k_fill_csr<<<gE, BT, 0, stream>>>(src, dst, row_ptr, cursor, csr_src);

    // W packs (tiny)
    k_wpack<F_IN, F_HID><<<16, BT, 0, stream>>>(W1, W1hi, W1lo);
    k_wpack<F_HID, F_OUT><<<16, BT, 0, stream>>>(W2, W2hi, W2lo);

    // Xs = dinv * x  (layer-1 prescale; aliases H1hi slot)
    k_prescale<<<gP, BT, 0, stream>>>(x, dinv, Xs);

    // layer 1: agg1 = dinv*(Xs[v] + sum Xs[s])  (split bf16 out)
    k_gather8<false, true><<<gG8, BT, 0, stream>>>(Xs, csr_src, row_ptr, dinv,
                                                   nullptr, nullptr, A1hi, A1lo);
    // H1 = relu(agg1 @ W1 + b1)  (split bf16 out; overwrites Xs region)
    k_gemm_mfma<F_IN, F_HID, true, true, true, false><<<NRB * 2, 64, 0, stream>>>(
        A1hi, A1lo, W1hi, W1lo, b1, nullptr, H1hi, H1lo, nullptr);
    // Hs2 = dinv * (H1 @ W2)  (f32, prescaled; aliases dead A1)
    k_gemm_mfma<F_HID, F_OUT, false, false, false, true><<<NRB, 64, 0, stream>>>(
        H1hi, H1lo, W2hi, W2lo, nullptr, dinv, nullptr, nullptr, H2);
    // out = dinv[v]*(Hs2[v] + sum Hs2[s]) + b2
    k_gather8<true, false><<<gG8, BT, 0, stream>>>(H2, csr_src, row_ptr, dinv,
                                                   b2, out, nullptr, nullptr);
}

// Round 9
// 256.216 us; speedup vs baseline: 1.1609x; 1.1609x over previous
//
#include <hip/hip_runtime.h>
#include <math.h>

// GCN: out = Ahat @ (relu(Ahat @ X @ W1 + b1)) @ W2 + b2
// R1: dst-CSR + gather aggregation (no f32 atomics).
// R2/R3: parallel scan; f32 GEMM retile.
// R4: split-bf16 (hi+lo) 3-pass MFMA GEMM: A@W ~= Ahi@Whi + Ahi@Wlo + Alo@Whi.
// R5: GEMM waves fattened to 64 rows x 128 cols (latency fix).
// R6: gather ILP + prescaled layer-2 (pure adds).
// R7: XCD feature-slicing -- REGRESSED (128B-line splitting + 8x index re-read
//     + worse divergence). Reverted.
// R8: one WAVE per node gather (no intra-wave degree divergence; 1 coalesced
//     512B row load per edge; x8 unroll). dinv folded into scan_blk; no
//     prescale kernel (per-edge dinv in gather-1, free per R6 data).

constexpr int NN = 50000;
constexpr int NE = 640000;
constexpr int NPAD = 50048;          // rows padded to 64
constexpr int F_IN = 128;
constexpr int F_HID = 256;
constexpr int F_OUT = 128;

typedef __attribute__((ext_vector_type(8))) short bf16x8;   // 8 bf16 = 4 VGPRs
typedef __attribute__((ext_vector_type(4))) float f32x4;
typedef __attribute__((ext_vector_type(8))) unsigned short u16x8;

__device__ inline unsigned short f2bf(float v) {  // RNE f32->bf16
    unsigned int u = __float_as_uint(v);
    return (unsigned short)((u + 0x7fff + ((u >> 16) & 1)) >> 16);
}
__device__ inline float bf2f(unsigned short h) {
    return __uint_as_float(((unsigned int)h) << 16);
}

__global__ void k_zero_deg(int* __restrict__ deg) {
    int v = blockIdx.x * blockDim.x + threadIdx.x;
    if (v < NN) deg[v] = 0;
}

__global__ void k_count_deg(const int* __restrict__ dst, int* __restrict__ deg) {
    int e = blockIdx.x * blockDim.x + threadIdx.x;
    if (e < NE) atomicAdd(&deg[dst[e]], 1);
}

// ---- parallel exclusive scan of deg[NN] -> row_ptr (+ dinv fused) ----
constexpr int SCB = 256;
constexpr int NCHUNK = (NN + SCB - 1) / SCB;  // 196

__global__ __launch_bounds__(SCB) void k_scan_blk(const int* __restrict__ deg,
                                                  int* __restrict__ row_ptr,
                                                  int* __restrict__ blk_sum,
                                                  float* __restrict__ dinv) {
    __shared__ int sm[SCB];
    int i = blockIdx.x * SCB + threadIdx.x;
    int v = (i < NN) ? deg[i] : 0;
    if (i < NN) dinv[i] = rsqrtf((float)(v + 1));  // +1 self loop
    sm[threadIdx.x] = v;
    __syncthreads();
    for (int off = 1; off < SCB; off <<= 1) {
        int t = (threadIdx.x >= off) ? sm[threadIdx.x - off] : 0;
        __syncthreads();
        sm[threadIdx.x] += t;
        __syncthreads();
    }
    if (i < NN) row_ptr[i] = sm[threadIdx.x] - v;
    if (threadIdx.x == SCB - 1) blk_sum[blockIdx.x] = sm[SCB - 1];
}

__global__ __launch_bounds__(SCB) void k_scan_top(const int* __restrict__ blk_sum,
                                                  int* __restrict__ blk_off) {
    __shared__ int sm[SCB];
    int v = (threadIdx.x < NCHUNK) ? blk_sum[threadIdx.x] : 0;
    sm[threadIdx.x] = v;
    __syncthreads();
    for (int off = 1; off < SCB; off <<= 1) {
        int t = (threadIdx.x >= off) ? sm[threadIdx.x - off] : 0;
        __syncthreads();
        sm[threadIdx.x] += t;
        __syncthreads();
    }
    if (threadIdx.x < NCHUNK) blk_off[threadIdx.x] = sm[threadIdx.x] - v;
}

__global__ __launch_bounds__(SCB) void k_scan_add(int* __restrict__ row_ptr,
                                                  const int* __restrict__ blk_off,
                                                  int* __restrict__ cursor) {
    int i = blockIdx.x * SCB + threadIdx.x;
    if (i < NN) {
        row_ptr[i] += blk_off[blockIdx.x];
        cursor[i] = 0;
    }
    if (i == 0) row_ptr[NN] = NE;
}

__global__ void k_fill_csr(const int* __restrict__ src, const int* __restrict__ dst,
                           const int* __restrict__ row_ptr, int* __restrict__ cursor,
                           int* __restrict__ csr_src) {
    int e = blockIdx.x * blockDim.x + threadIdx.x;
    if (e >= NE) return;
    int d = dst[e];
    int slot = row_ptr[d] + atomicAdd(&cursor[d], 1);
    csr_src[slot] = src[e];
}

// Pack W[K][N] f32 -> fragment-native bf16 hi/lo: idx = ((kt*NT+nt)*64+lane)*8+e
template <int K, int N>
__global__ __launch_bounds__(256) void k_wpack(const float* __restrict__ W,
                                               unsigned short* __restrict__ hi,
                                               unsigned short* __restrict__ lo) {
    constexpr int NT = N / 16, KT = K / 32;
    int t = blockIdx.x * 256 + threadIdx.x;
    if (t >= KT * NT * 64) return;
    int lane = t & 63, nt = (t >> 6) % NT, kt = (t >> 6) / NT;
    int col = nt * 16 + (lane & 15), kg = lane >> 4;
    unsigned short hb[8], lb[8];
#pragma unroll
    for (int e = 0; e < 8; ++e) {
        int k = kt * 32 + kg * 8 + e;
        float v = W[(size_t)k * N + col];
        unsigned short h = f2bf(v);
        hb[e] = h;
        lb[e] = f2bf(v - bf2f(h));
    }
    *reinterpret_cast<u16x8*>(hi + (size_t)t * 8) = *reinterpret_cast<u16x8*>(hb);
    *reinterpret_cast<u16x8*>(lo + (size_t)t * 8) = *reinterpret_cast<u16x8*>(lb);
}

// One-wave-per-node aggregation over 128 feats (lane owns float2 = cols 2l,2l+1).
// PRESCALED=false: acc = dinv[v]*feat[v] + sum dinv[s]*feat[s]; out = dinv[v]*acc (+b)
// PRESCALED=true:  rows carry dinv already: acc = feat[v] + sum feat[s]; same epilogue.
// Per edge: ONE coalesced 512B row load; index/dinv loads wave-uniform; x8 unroll.
template <bool BIAS, bool SPLITOUT, bool PRESCALED>
__global__ __launch_bounds__(256) void k_gatherw(const float* __restrict__ feat,
                                                 const int* __restrict__ csr_src,
                                                 const int* __restrict__ row_ptr,
                                                 const float* __restrict__ dinv,
                                                 const float* __restrict__ bias,
                                                 float* __restrict__ out_f,
                                                 unsigned short* __restrict__ out_hi,
                                                 unsigned short* __restrict__ out_lo) {
    const int wave = threadIdx.x >> 6;
    const int lane = threadIdx.x & 63;
    const int node = blockIdx.x * 4 + wave;
    if (node >= NN) return;
    const float2* f2 = reinterpret_cast<const float2*>(feat);
    const float di = dinv[node];
    float2 a = f2[(size_t)node * 64 + lane];
    if (!PRESCALED) { a.x *= di; a.y *= di; }
    int j = row_ptr[node];
    const int end = row_ptr[node + 1];
    for (; j + 7 < end; j += 8) {
        int s0 = csr_src[j + 0], s1 = csr_src[j + 1];
        int s2 = csr_src[j + 2], s3 = csr_src[j + 3];
        int s4 = csr_src[j + 4], s5 = csr_src[j + 5];
        int s6 = csr_src[j + 6], s7 = csr_src[j + 7];
        float2 r0 = f2[(size_t)s0 * 64 + lane], r1 = f2[(size_t)s1 * 64 + lane];
        float2 r2 = f2[(size_t)s2 * 64 + lane], r3 = f2[(size_t)s3 * 64 + lane];
        float2 r4 = f2[(size_t)s4 * 64 + lane], r5 = f2[(size_t)s5 * 64 + lane];
        float2 r6 = f2[(size_t)s6 * 64 + lane], r7 = f2[(size_t)s7 * 64 + lane];
        if (PRESCALED) {
            a.x += ((r0.x + r1.x) + (r2.x + r3.x)) + ((r4.x + r5.x) + (r6.x + r7.x));
            a.y += ((r0.y + r1.y) + (r2.y + r3.y)) + ((r4.y + r5.y) + (r6.y + r7.y));
        } else {
            float n0 = dinv[s0], n1 = dinv[s1], n2 = dinv[s2], n3 = dinv[s3];
            float n4 = dinv[s4], n5 = dinv[s5], n6 = dinv[s6], n7 = dinv[s7];
            a.x += n0 * r0.x + n1 * r1.x + n2 * r2.x + n3 * r3.x
                 + n4 * r4.x + n5 * r5.x + n6 * r6.x + n7 * r7.x;
            a.y += n0 * r0.y + n1 * r1.y + n2 * r2.y + n3 * r3.y
                 + n4 * r4.y + n5 * r5.y + n6 * r6.y + n7 * r7.y;
        }
    }
    for (; j < end; ++j) {
        int s = csr_src[j];
        float2 r = f2[(size_t)s * 64 + lane];
        float n = PRESCALED ? 1.f : dinv[s];
        a.x += n * r.x;
        a.y += n * r.y;
    }
    a.x *= di; a.y *= di;
    if (BIAS) {
        float2 b = reinterpret_cast<const float2*>(bias)[lane];
        a.x += b.x; a.y += b.y;
    }
    if (SPLITOUT) {
        ushort2 hh, ll;
        hh.x = f2bf(a.x); ll.x = f2bf(a.x - bf2f(hh.x));
        hh.y = f2bf(a.y); ll.y = f2bf(a.y - bf2f(hh.y));
        *reinterpret_cast<ushort2*>(out_hi + (size_t)node * 128 + lane * 2) = hh;
        *reinterpret_cast<ushort2*>(out_lo + (size_t)node * 128 + lane * 2) = ll;
    } else {
        reinterpret_cast<float2*>(out_f)[(size_t)node * 64 + lane] = a;
    }
}

// C[M,N] = A[M,K] @ W[K,N] via 3-pass split-bf16 MFMA 16x16x32.
// One wave per block; wave owns 64 rows x 128 cols (acc[4][8]).
// PRESCALE: multiply output row r by dscale[r] (folds dinv for gather-2).
template <int K, int N, bool RELU, bool BIAS, bool SPLITOUT, bool PRESCALE>
__global__ __launch_bounds__(64) void k_gemm_mfma(
    const unsigned short* __restrict__ Ahi, const unsigned short* __restrict__ Alo,
    const unsigned short* __restrict__ Bhi, const unsigned short* __restrict__ Blo,
    const float* __restrict__ bias, const float* __restrict__ dscale,
    unsigned short* __restrict__ Chi, unsigned short* __restrict__ Clo,
    float* __restrict__ Cf) {
    constexpr int NTall = N / 16, KT = K / 32;
    constexpr int WR = 4;
    constexpr int WC = 8;
    constexpr int NRB = NPAD / 64;
    const int lane = threadIdx.x;
    const int rb = blockIdx.x % NRB;
    const int cb = blockIdx.x / NRB;
    const int row0 = rb * 64;
    const int ct0 = cb * WC;
    const int r16 = lane & 15;
    const int kg = lane >> 4;

    f32x4 acc[WR][WC];
#pragma unroll
    for (int rt = 0; rt < WR; ++rt)
#pragma unroll
        for (int ct = 0; ct < WC; ++ct) acc[rt][ct] = (f32x4){0.f, 0.f, 0.f, 0.f};

    const unsigned short* pa_hi = Ahi + (size_t)(row0 + r16) * K + kg * 8;
    const unsigned short* pa_lo = Alo + (size_t)(row0 + r16) * K + kg * 8;
    const unsigned short* pb_hi = Bhi + (size_t)lane * 8;
    const unsigned short* pb_lo = Blo + (size_t)lane * 8;

#pragma unroll
    for (int kt = 0; kt < KT; ++kt) {
        bf16x8 ah[WR], al[WR];
#pragma unroll
        for (int rt = 0; rt < WR; ++rt) {
            ah[rt] = *reinterpret_cast<const bf16x8*>(pa_hi + (size_t)rt * 16 * K + kt * 32);
            al[rt] = *reinterpret_cast<const bf16x8*>(pa_lo + (size_t)rt * 16 * K + kt * 32);
        }
#pragma unroll
        for (int ct = 0; ct < WC; ++ct) {
            const int nt = ct0 + ct;
            bf16x8 bh = *reinterpret_cast<const bf16x8*>(pb_hi + (size_t)(kt * NTall + nt) * 512);
            bf16x8 bl = *reinterpret_cast<const bf16x8*>(pb_lo + (size_t)(kt * NTall + nt) * 512);
#pragma unroll
            for (int rt = 0; rt < WR; ++rt) {
                acc[rt][ct] = __builtin_amdgcn_mfma_f32_16x16x32_bf16(ah[rt], bh, acc[rt][ct], 0, 0, 0);
                acc[rt][ct] = __builtin_amdgcn_mfma_f32_16x16x32_bf16(ah[rt], bl, acc[rt][ct], 0, 0, 0);
                acc[rt][ct] = __builtin_amdgcn_mfma_f32_16x16x32_bf16(al[rt], bh, acc[rt][ct], 0, 0, 0);
            }
        }
    }

    // C/D layout: col = lane&15, row = (lane>>4)*4 + i
    const int ccol = lane & 15;
#pragma unroll
    for (int rt = 0; rt < WR; ++rt) {
        const int crow0 = row0 + rt * 16 + (lane >> 4) * 4;
#pragma unroll
        for (int ct = 0; ct < WC; ++ct) {
            int col = (ct0 + ct) * 16 + ccol;
            float bv = BIAS ? bias[col] : 0.f;
#pragma unroll
            for (int i = 0; i < 4; ++i) {
                float v = acc[rt][ct][i] + bv;
                if (RELU) v = fmaxf(v, 0.f);
                if (PRESCALE) v *= dscale[crow0 + i];
                size_t idx = (size_t)(crow0 + i) * N + col;
                if (SPLITOUT) {
                    unsigned short h = f2bf(v);
                    Chi[idx] = h;
                    Clo[idx] = f2bf(v - bf2f(h));
                } else {
                    Cf[idx] = v;
                }
            }
        }
    }
}

extern "C" void kernel_launch(void* const* d_in, const int* in_sizes, int n_in,
                              void* d_out, int out_size, void* d_ws, size_t ws_size,
                              hipStream_t stream) {
    const float* x  = (const float*)d_in[0];
    const int*   ei = (const int*)d_in[1];
    const float* W1 = (const float*)d_in[2];
    const float* b1 = (const float*)d_in[3];
    const float* W2 = (const float*)d_in[4];
    const float* b2 = (const float*)d_in[5];
    float* out = (float*)d_out;

    const int* src = ei;
    const int* dst = ei + NE;

    // workspace layout (all offsets 256-aligned):
    char* ws = (char*)d_ws;
    int*   deg     = (int*)ws;                               // 200 KB
    int*   cursor  = (int*)(ws + 262144);
    int*   row_ptr = (int*)(ws + 524288);
    float* dinv    = (float*)(ws + 786432);
    int*   csr_src = (int*)(ws + 1048576);                   // 2.56 MB
    int*   blk_sum = (int*)(ws + 3670016);
    int*   blk_off = (int*)(ws + 3674112);
    unsigned short* W1hi = (unsigned short*)(ws + 3678208);  // 64 KB each
    unsigned short* W1lo = (unsigned short*)(ws + 3743744);
    unsigned short* W2hi = (unsigned short*)(ws + 3809280);
    unsigned short* W2lo = (unsigned short*)(ws + 3874816);
    unsigned short* A1hi = (unsigned short*)(ws + 4194304);  // NPAD*128*2 = 12.81 MB
    unsigned short* A1lo = (unsigned short*)(ws + 17006592); // 12.81 MB
    unsigned short* H1hi = (unsigned short*)(ws + 29818880); // NPAD*256*2 = 25.62 MB
    unsigned short* H1lo = (unsigned short*)(ws + 55443456); // 25.62 MB
    float* H2 = (float*)(ws + 4194304);   // aliases A1hi+A1lo (dead after GEMM-1)

    constexpr int BT = 256;
    const int gN = (NN + BT - 1) / BT;   // 196
    const int gE = (NE + BT - 1) / BT;   // 2500
    const int gW = (NN + 3) / 4;         // 12500 (1 wave per node, 4 waves/block)
    constexpr int NRB = NPAD / 64;       // 782

    // CSR build (dinv fused into scan_blk)
    k_zero_deg<<<gN, BT, 0, stream>>>(deg);
    k_count_deg<<<gE, BT, 0, stream>>>(dst, deg);
    k_scan_blk<<<NCHUNK, SCB, 0, stream>>>(deg, row_ptr, blk_sum, dinv);
    k_scan_top<<<1, SCB, 0, stream>>>(blk_sum, blk_off);
    k_scan_add<<<NCHUNK, SCB, 0, stream>>>(row_ptr, blk_off, cursor);
    k_fill_csr<<<gE, BT, 0, stream>>>(src, dst, row_ptr, cursor, csr_src);

    // W packs (tiny)
    k_wpack<F_IN, F_HID><<<16, BT, 0, stream>>>(W1, W1hi, W1lo);
    k_wpack<F_HID, F_OUT><<<16, BT, 0, stream>>>(W2, W2hi, W2lo);

    // layer 1: agg1 = dinv[v]*(dinv[v]*x[v] + sum dinv[s]*x[s])  (split bf16 out)
    k_gatherw<false, true, false><<<gW, BT, 0, stream>>>(x, csr_src, row_ptr, dinv,
                                                         nullptr, nullptr, A1hi, A1lo);
    // H1 = relu(agg1 @ W1 + b1)  (split bf16 out)
    k_gemm_mfma<F_IN, F_HID, true, true, true, false><<<NRB * 2, 64, 0, stream>>>(
        A1hi, A1lo, W1hi, W1lo, b1, nullptr, H1hi, H1lo, nullptr);
    // Hs2 = dinv * (H1 @ W2)  (f32, prescaled; aliases dead A1)
    k_gemm_mfma<F_HID, F_OUT, false, false, false, true><<<NRB, 64, 0, stream>>>(
        H1hi, H1lo, W2hi, W2lo, nullptr, dinv, nullptr, nullptr, H2);
    // out = dinv[v]*(Hs2[v] + sum Hs2[s]) + b2
    k_gatherw<true, false, true><<<gW, BT, 0, stream>>>(H2, csr_src, row_ptr, dinv,
                                                        b2, out, nullptr, nullptr);
}